// Round 1
// baseline (90.355 us; speedup 1.0000x reference)
//
#include <hip/hip_runtime.h>

#define NSEQ   16
#define KVH    8
#define NG     4      // query heads per kv head
#define HD     128
#define BS     16
#define MAXB   256
#define PART   256
#define NPART  16
#define PSTRIDE 520   // floats per partition record: o[512], l[4], m, pad
#define SCALE_F 0.08838834764831845f

// Kernel 1: per (seq, kv_head, partition) compute partial attention.
// Thread = one token for QK; thread = (d, token-half) for PV.
__global__ __launch_bounds__(256) void pa_partial_kernel(
    const float* __restrict__ query,
    const float* __restrict__ key,
    const float* __restrict__ value,
    const float* __restrict__ key_cache,
    const float* __restrict__ value_cache,
    const int*   __restrict__ block_tables,
    const int*   __restrict__ context_lens,
    float*       __restrict__ ws)
{
    const int bid = blockIdx.x;
    const int p   = bid & (NPART - 1);
    const int kvh = (bid >> 4) & (KVH - 1);
    const int s   = bid >> 7;

    const int ctx = context_lens[s];
    const int t0  = p * PART;
    if (t0 >= ctx) return;

    __shared__ float q_lds[NG * HD];    // 512 floats: Q for 4 heads (reused for half-combine)
    __shared__ float p_lds[NG * PART];  // 1024 floats: probabilities
    __shared__ float red[20];           // [0..3] wave max, [4..19] wave l-sums

    const int tid = threadIdx.x;

    // ---- stage Q (coalesced float2 x 256 threads = 512 floats) ----
    const float* qsrc = query + (size_t)s * (KVH * NG * HD) + (size_t)kvh * (NG * HD);
    ((float2*)q_lds)[tid] = ((const float2*)qsrc)[tid];
    __syncthreads();

    // ---- QK: one token per thread ----
    const int t    = t0 + tid;                       // always < 4096, in-bounds reads
    const int bt   = block_tables[s * MAXB + (t >> 4)];
    const int off  = t & 15;
    const bool isnew = (t == ctx - 1);               // this token's K/V come from key/value inputs
    // cache element (j,off,x) at j*128 + off*8 + x ; new-key element d at d = j*8 + x
    const float* kb = isnew ? (key + ((size_t)s * KVH + kvh) * HD)
                            : (key_cache + (size_t)bt * (KVH * HD * BS)
                                         + (size_t)kvh * (HD * BS) + off * 8);
    const int js = isnew ? 8 : 128;

    float sc0 = 0.f, sc1 = 0.f, sc2 = 0.f, sc3 = 0.f;
    const float4* q4 = (const float4*)q_lds;
    #pragma unroll
    for (int j = 0; j < 16; ++j) {
        const float4 ka = *(const float4*)(kb + j * js);
        const float4 kc = *(const float4*)(kb + j * js + 4);
        float4 qa, qb;
        qa = q4[0 * 32 + j * 2]; qb = q4[0 * 32 + j * 2 + 1];
        sc0 += qa.x*ka.x + qa.y*ka.y + qa.z*ka.z + qa.w*ka.w
             + qb.x*kc.x + qb.y*kc.y + qb.z*kc.z + qb.w*kc.w;
        qa = q4[1 * 32 + j * 2]; qb = q4[1 * 32 + j * 2 + 1];
        sc1 += qa.x*ka.x + qa.y*ka.y + qa.z*ka.z + qa.w*ka.w
             + qb.x*kc.x + qb.y*kc.y + qb.z*kc.z + qb.w*kc.w;
        qa = q4[2 * 32 + j * 2]; qb = q4[2 * 32 + j * 2 + 1];
        sc2 += qa.x*ka.x + qa.y*ka.y + qa.z*ka.z + qa.w*ka.w
             + qb.x*kc.x + qb.y*kc.y + qb.z*kc.z + qb.w*kc.w;
        qa = q4[3 * 32 + j * 2]; qb = q4[3 * 32 + j * 2 + 1];
        sc3 += qa.x*ka.x + qa.y*ka.y + qa.z*ka.z + qa.w*ka.w
             + qb.x*kc.x + qb.y*kc.y + qb.z*kc.z + qb.w*kc.w;
    }

    float mval;
    if (t < ctx) {
        sc0 *= SCALE_F; sc1 *= SCALE_F; sc2 *= SCALE_F; sc3 *= SCALE_F;
        mval = fmaxf(fmaxf(sc0, sc1), fmaxf(sc2, sc3));
    } else {
        sc0 = sc1 = sc2 = sc3 = -1e30f;
        mval = -1e30f;
    }

    // shared max over the whole partition (valid across heads: any m >= true max works)
    #pragma unroll
    for (int o = 32; o; o >>= 1) mval = fmaxf(mval, __shfl_xor(mval, o));
    const int wave = tid >> 6;
    if ((tid & 63) == 0) red[wave] = mval;
    __syncthreads();
    const float m = fmaxf(fmaxf(red[0], red[1]), fmaxf(red[2], red[3]));

    const float p0 = __expf(sc0 - m);
    const float p1 = __expf(sc1 - m);
    const float p2 = __expf(sc2 - m);
    const float p3 = __expf(sc3 - m);
    p_lds[0 * PART + tid] = p0;
    p_lds[1 * PART + tid] = p1;
    p_lds[2 * PART + tid] = p2;
    p_lds[3 * PART + tid] = p3;

    // l[g] partial sums per wave
    float l0 = p0, l1 = p1, l2 = p2, l3 = p3;
    #pragma unroll
    for (int o = 32; o; o >>= 1) {
        l0 += __shfl_xor(l0, o);
        l1 += __shfl_xor(l1, o);
        l2 += __shfl_xor(l2, o);
        l3 += __shfl_xor(l3, o);
    }
    if ((tid & 63) == 0) {
        red[4 + wave * 4 + 0] = l0;
        red[4 + wave * 4 + 1] = l1;
        red[4 + wave * 4 + 2] = l2;
        red[4 + wave * 4 + 3] = l3;
    }
    __syncthreads();   // p_lds + red ready; q_lds free after this point

    // ---- PV: thread = (d, token half) ----
    const int d = tid & 127;
    const int h = tid >> 7;
    float a0 = 0.f, a1 = 0.f, a2 = 0.f, a3 = 0.f;
    const float4* pl4 = (const float4*)p_lds;
    #pragma unroll 2
    for (int b = 0; b < 8; ++b) {
        const int tb   = h * 8 + b;                  // 16-token block within partition
        const int tg0  = t0 + tb * 16;
        const int btv  = block_tables[s * MAXB + (tg0 >> 4)];
        const float* vb = value_cache + (size_t)btv * (KVH * HD * BS)
                                      + (size_t)kvh * (HD * BS) + d * BS;
        #pragma unroll
        for (int c = 0; c < 4; ++c) {
            const float4 v4  = *(const float4*)(vb + c * 4);
            const float4 pg0 = pl4[0 * 64 + tb * 4 + c];
            const float4 pg1 = pl4[1 * 64 + tb * 4 + c];
            const float4 pg2 = pl4[2 * 64 + tb * 4 + c];
            const float4 pg3 = pl4[3 * 64 + tb * 4 + c];
            a0 += pg0.x*v4.x + pg0.y*v4.y + pg0.z*v4.z + pg0.w*v4.w;
            a1 += pg1.x*v4.x + pg1.y*v4.y + pg1.z*v4.z + pg1.w*v4.w;
            a2 += pg2.x*v4.x + pg2.y*v4.y + pg2.z*v4.z + pg2.w*v4.w;
            a3 += pg3.x*v4.x + pg3.y*v4.y + pg3.z*v4.z + pg3.w*v4.w;
        }
    }

    // new-token V correction: replace stale cache value at token ctx-1 with `value` input
    const int tlnew = ctx - 1 - t0;
    if (tlnew >= h * 128 && tlnew < h * 128 + 128) {
        const int btn = block_tables[s * MAXB + ((ctx - 1) >> 4)];
        const float vold = value_cache[(size_t)btn * (KVH * HD * BS)
                                       + (size_t)kvh * (HD * BS) + d * BS + ((ctx - 1) & 15)];
        const float vnew = value[((size_t)s * KVH + kvh) * HD + d];
        const float dv = vnew - vold;
        a0 += p_lds[0 * PART + tlnew] * dv;
        a1 += p_lds[1 * PART + tlnew] * dv;
        a2 += p_lds[2 * PART + tlnew] * dv;
        a3 += p_lds[3 * PART + tlnew] * dv;
    }

    // combine halves via q_lds (free now)
    if (h == 1) {
        q_lds[0 * HD + d] = a0;
        q_lds[1 * HD + d] = a1;
        q_lds[2 * HD + d] = a2;
        q_lds[3 * HD + d] = a3;
    }
    __syncthreads();

    float* rec = ws + (size_t)bid * PSTRIDE;
    if (h == 0) {
        a0 += q_lds[0 * HD + d];
        a1 += q_lds[1 * HD + d];
        a2 += q_lds[2 * HD + d];
        a3 += q_lds[3 * HD + d];
        rec[0 * HD + d] = a0;
        rec[1 * HD + d] = a1;
        rec[2 * HD + d] = a2;
        rec[3 * HD + d] = a3;
    }
    if (tid < 4) {
        rec[512 + tid] = red[4 + tid] + red[8 + tid] + red[12 + tid] + red[16 + tid];
    }
    if (tid == 4) rec[516] = m;
}

// Kernel 2: LSE-combine partitions -> output
__global__ __launch_bounds__(512) void pa_reduce_kernel(
    const float* __restrict__ ws,
    const int*   __restrict__ context_lens,
    float*       __restrict__ out)
{
    const int pair = blockIdx.x;        // s*8 + kvh
    const int s    = pair >> 3;
    const int kvh  = pair & 7;
    const int ctx  = context_lens[s];
    const int np   = (ctx + PART - 1) / PART;

    const int tid = threadIdx.x;
    const int g = tid >> 7;
    const int d = tid & 127;

    const float* base = ws + (size_t)pair * NPART * PSTRIDE;

    float M = -1e30f;
    for (int p2 = 0; p2 < np; ++p2) M = fmaxf(M, base[p2 * PSTRIDE + 516]);

    float L = 0.f, acc = 0.f;
    for (int p2 = 0; p2 < np; ++p2) {
        const float* rec = base + p2 * PSTRIDE;
        const float w = __expf(rec[516] - M);
        L   += w * rec[512 + g];
        acc += w * rec[g * HD + d];
    }

    out[(size_t)s * (KVH * NG * HD) + (size_t)(kvh * NG + g) * HD + d] = acc / L;
}

extern "C" void kernel_launch(void* const* d_in, const int* in_sizes, int n_in,
                              void* d_out, int out_size, void* d_ws, size_t ws_size,
                              hipStream_t stream) {
    const float* query       = (const float*)d_in[0];
    const float* key         = (const float*)d_in[1];
    const float* value       = (const float*)d_in[2];
    const float* key_cache   = (const float*)d_in[3];
    const float* value_cache = (const float*)d_in[4];
    const int*   block_tables  = (const int*)d_in[5];
    const int*   context_lens  = (const int*)d_in[6];
    // d_in[7] slot_mapping unused: slot is derivable from context_lens + block_tables

    float* out = (float*)d_out;
    float* ws  = (float*)d_ws;   // needs 16*8*16*520*4 = 4.26 MB

    pa_partial_kernel<<<NSEQ * KVH * NPART, 256, 0, stream>>>(
        query, key, value, key_cache, value_cache, block_tables, context_lens, ws);
    pa_reduce_kernel<<<NSEQ * KVH, 512, 0, stream>>>(ws, context_lens, out);
}

// Round 2
// 90.232 us; speedup vs baseline: 1.0014x; 1.0014x over previous
//
#include <hip/hip_runtime.h>

#define NSEQ   16
#define KVH    8
#define NG     4      // query heads per kv head
#define HD     128
#define BS     16
#define MAXB   256
#define PART   256
#define NPART  16
#define PSTRIDE 520   // floats per partition record: o[512], l[4], m, pad
#define SCALE_F 0.08838834764831845f

// Kernel 1: per (seq, kv_head, partition) compute partial attention.
// Thread = one token for QK; thread = (d, token-half) for PV.
// Q is read via the scalar path (wave-uniform global indices) -> no LDS for Q.
__global__ __launch_bounds__(256) void pa_partial_kernel(
    const float* __restrict__ query,
    const float* __restrict__ key,
    const float* __restrict__ value,
    const float* __restrict__ key_cache,
    const float* __restrict__ value_cache,
    const int*   __restrict__ block_tables,
    const int*   __restrict__ context_lens,
    float*       __restrict__ ws)
{
    const int bid = blockIdx.x;
    const int p   = bid & (NPART - 1);
    const int kvh = (bid >> 4) & (KVH - 1);
    const int s   = bid >> 7;

    const int ctx = context_lens[s];
    const int t0  = p * PART;
    if (t0 >= ctx) return;

    __shared__ float p_lds[NG * PART];  // probabilities
    __shared__ float o_lds[NG * HD];    // half-combine buffer
    __shared__ float red[20];           // [0..3] wave max, [4..19] wave l-sums

    const int tid = threadIdx.x;
    const float* q = query + (size_t)s * (KVH * NG * HD) + (size_t)kvh * (NG * HD);

    // ---- QK: one token per thread, constant cache stride ----
    const int t    = t0 + tid;                       // always < 4096, in-bounds reads
    const int bt   = block_tables[s * MAXB + (t >> 4)];
    const int off  = t & 15;
    const float* kb = key_cache + (size_t)bt * (KVH * HD * BS)
                                + (size_t)kvh * (HD * BS) + off * 8;

    float sc[NG] = {0.f, 0.f, 0.f, 0.f};
    #pragma unroll
    for (int j = 0; j < 16; ++j) {
        const float4 ka = *(const float4*)(kb + j * 128);
        const float4 kc = *(const float4*)(kb + j * 128 + 4);
        #pragma unroll
        for (int g = 0; g < NG; ++g) {
            // q indices are wave-uniform -> scalar loads, SGPR operands
            sc[g] += q[g * HD + j * 8 + 0] * ka.x + q[g * HD + j * 8 + 1] * ka.y
                   + q[g * HD + j * 8 + 2] * ka.z + q[g * HD + j * 8 + 3] * ka.w
                   + q[g * HD + j * 8 + 4] * kc.x + q[g * HD + j * 8 + 5] * kc.y
                   + q[g * HD + j * 8 + 6] * kc.z + q[g * HD + j * 8 + 7] * kc.w;
        }
    }

    // new-token K correction: token ctx-1's key comes from the `key` input
    if (t == ctx - 1) {
        const float4* kn4 = (const float4*)(key + ((size_t)s * KVH + kvh) * HD);
        float ns[NG] = {0.f, 0.f, 0.f, 0.f};
        #pragma unroll
        for (int c = 0; c < 32; ++c) {
            const float4 k4 = kn4[c];
            #pragma unroll
            for (int g = 0; g < NG; ++g) {
                ns[g] += q[g * HD + c * 4 + 0] * k4.x + q[g * HD + c * 4 + 1] * k4.y
                       + q[g * HD + c * 4 + 2] * k4.z + q[g * HD + c * 4 + 3] * k4.w;
            }
        }
        #pragma unroll
        for (int g = 0; g < NG; ++g) sc[g] = ns[g];
    }

    float mval;
    if (t < ctx) {
        #pragma unroll
        for (int g = 0; g < NG; ++g) sc[g] *= SCALE_F;
        mval = fmaxf(fmaxf(sc[0], sc[1]), fmaxf(sc[2], sc[3]));
    } else {
        #pragma unroll
        for (int g = 0; g < NG; ++g) sc[g] = -1e30f;
        mval = -1e30f;
    }

    // block max (valid across heads: any m >= true max works)
    #pragma unroll
    for (int o = 32; o; o >>= 1) mval = fmaxf(mval, __shfl_xor(mval, o));
    const int wave = tid >> 6;
    if ((tid & 63) == 0) red[wave] = mval;
    __syncthreads();
    const float m = fmaxf(fmaxf(red[0], red[1]), fmaxf(red[2], red[3]));

    const float p0 = __expf(sc[0] - m);
    const float p1 = __expf(sc[1] - m);
    const float p2 = __expf(sc[2] - m);
    const float p3 = __expf(sc[3] - m);
    p_lds[0 * PART + tid] = p0;
    p_lds[1 * PART + tid] = p1;
    p_lds[2 * PART + tid] = p2;
    p_lds[3 * PART + tid] = p3;

    float l0 = p0, l1 = p1, l2 = p2, l3 = p3;
    #pragma unroll
    for (int o = 32; o; o >>= 1) {
        l0 += __shfl_xor(l0, o);
        l1 += __shfl_xor(l1, o);
        l2 += __shfl_xor(l2, o);
        l3 += __shfl_xor(l3, o);
    }
    if ((tid & 63) == 0) {
        red[4 + wave * 4 + 0] = l0;
        red[4 + wave * 4 + 1] = l1;
        red[4 + wave * 4 + 2] = l2;
        red[4 + wave * 4 + 3] = l3;
    }
    __syncthreads();   // p_lds + red ready

    // ---- PV: thread = (d, token half) ----
    const int d = tid & 127;
    const int h = tid >> 7;

    // hoist wave-uniform block-table reads
    int btv[8];
    #pragma unroll
    for (int b = 0; b < 8; ++b)
        btv[b] = block_tables[s * MAXB + (t0 >> 4) + h * 8 + b];

    float a0 = 0.f, a1 = 0.f, a2 = 0.f, a3 = 0.f;
    const float4* pl4 = (const float4*)p_lds;
    #pragma unroll 2
    for (int b = 0; b < 8; ++b) {
        const int tb = h * 8 + b;                  // 16-token block within partition
        const float* vb = value_cache + (size_t)btv[b] * (KVH * HD * BS)
                                      + (size_t)kvh * (HD * BS) + d * BS;
        #pragma unroll
        for (int c = 0; c < 4; ++c) {
            const float4 v4  = *(const float4*)(vb + c * 4);
            const float4 pg0 = pl4[0 * 64 + tb * 4 + c];
            const float4 pg1 = pl4[1 * 64 + tb * 4 + c];
            const float4 pg2 = pl4[2 * 64 + tb * 4 + c];
            const float4 pg3 = pl4[3 * 64 + tb * 4 + c];
            a0 += pg0.x*v4.x + pg0.y*v4.y + pg0.z*v4.z + pg0.w*v4.w;
            a1 += pg1.x*v4.x + pg1.y*v4.y + pg1.z*v4.z + pg1.w*v4.w;
            a2 += pg2.x*v4.x + pg2.y*v4.y + pg2.z*v4.z + pg2.w*v4.w;
            a3 += pg3.x*v4.x + pg3.y*v4.y + pg3.z*v4.z + pg3.w*v4.w;
        }
    }

    // new-token V correction: replace stale cache value at token ctx-1
    const int tlnew = ctx - 1 - t0;
    if (tlnew >= h * 128 && tlnew < h * 128 + 128) {
        const int btn = block_tables[s * MAXB + ((ctx - 1) >> 4)];
        const float vold = value_cache[(size_t)btn * (KVH * HD * BS)
                                       + (size_t)kvh * (HD * BS) + d * BS + ((ctx - 1) & 15)];
        const float vnew = value[((size_t)s * KVH + kvh) * HD + d];
        const float dv = vnew - vold;
        a0 += p_lds[0 * PART + tlnew] * dv;
        a1 += p_lds[1 * PART + tlnew] * dv;
        a2 += p_lds[2 * PART + tlnew] * dv;
        a3 += p_lds[3 * PART + tlnew] * dv;
    }

    // combine halves via o_lds
    if (h == 1) {
        o_lds[0 * HD + d] = a0;
        o_lds[1 * HD + d] = a1;
        o_lds[2 * HD + d] = a2;
        o_lds[3 * HD + d] = a3;
    }
    __syncthreads();

    float* rec = ws + (size_t)bid * PSTRIDE;
    if (h == 0) {
        a0 += o_lds[0 * HD + d];
        a1 += o_lds[1 * HD + d];
        a2 += o_lds[2 * HD + d];
        a3 += o_lds[3 * HD + d];
        rec[0 * HD + d] = a0;
        rec[1 * HD + d] = a1;
        rec[2 * HD + d] = a2;
        rec[3 * HD + d] = a3;
    }
    if (tid < 4) {
        rec[512 + tid] = red[4 + tid] + red[8 + tid] + red[12 + tid] + red[16 + tid];
    }
    if (tid == 4) rec[516] = m;
}

// Kernel 2: LSE-combine partitions -> output. One (seq, kvh, g) per block.
__global__ __launch_bounds__(128) void pa_reduce_kernel(
    const float* __restrict__ ws,
    const int*   __restrict__ context_lens,
    float*       __restrict__ out)
{
    const int b    = blockIdx.x;        // ((s*KVH)+kvh)*NG + g
    const int g    = b & 3;
    const int pair = b >> 2;            // s*KVH + kvh
    const int s    = pair >> 3;
    const int kvh  = pair & 7;
    const int ctx  = context_lens[s];
    const int np   = (ctx + PART - 1) / PART;

    const int d = threadIdx.x;
    const float* base = ws + (size_t)pair * NPART * PSTRIDE;

    float M = -1e30f;
    for (int p2 = 0; p2 < np; ++p2) M = fmaxf(M, base[p2 * PSTRIDE + 516]);

    float L = 0.f, acc = 0.f;
    for (int p2 = 0; p2 < np; ++p2) {
        const float* rec = base + p2 * PSTRIDE;
        const float w = __expf(rec[516] - M);
        L   += w * rec[512 + g];
        acc += w * rec[g * HD + d];
    }

    out[(size_t)s * (KVH * NG * HD) + (size_t)(kvh * NG + g) * HD + d] = acc / L;
}

extern "C" void kernel_launch(void* const* d_in, const int* in_sizes, int n_in,
                              void* d_out, int out_size, void* d_ws, size_t ws_size,
                              hipStream_t stream) {
    const float* query       = (const float*)d_in[0];
    const float* key         = (const float*)d_in[1];
    const float* value       = (const float*)d_in[2];
    const float* key_cache   = (const float*)d_in[3];
    const float* value_cache = (const float*)d_in[4];
    const int*   block_tables  = (const int*)d_in[5];
    const int*   context_lens  = (const int*)d_in[6];
    // d_in[7] slot_mapping unused: slot is derivable from context_lens + block_tables

    float* out = (float*)d_out;
    float* ws  = (float*)d_ws;   // needs 16*8*16*520*4 = 4.26 MB

    pa_partial_kernel<<<NSEQ * KVH * NPART, 256, 0, stream>>>(
        query, key, value, key_cache, value_cache, block_tables, context_lens, ws);
    pa_reduce_kernel<<<NSEQ * KVH * NG, 128, 0, stream>>>(ws, context_lens, out);
}

// Round 3
// 85.929 us; speedup vs baseline: 1.0515x; 1.0501x over previous
//
#include <hip/hip_runtime.h>

#define NSEQ   16
#define KVH    8
#define NG     4      // query heads per kv head
#define HD     128
#define BS     16
#define MAXB   256
#define PART   256    // tokens per block (4 waves x 64)
#define NPART  16
#define WPT    64     // tokens per wave
#define PSTRIDE 520   // floats per partition record: o[512], l[4], m, pad
#define SCALE_F 0.08838834764831845f

// Kernel 1: per (seq, kv_head, partition). Four INDEPENDENT waves, each owning
// a 64-token slice with wave-local softmax (shfl only, no barriers). Single
// barrier at the end for the 4-way LSE merge. Goal: waves drift out of phase
// so the CU's memory pipe never idles at phase boundaries.
__global__ __launch_bounds__(256) void pa_partial_kernel(
    const float* __restrict__ query,
    const float* __restrict__ key,
    const float* __restrict__ value,
    const float* __restrict__ key_cache,
    const float* __restrict__ value_cache,
    const int*   __restrict__ block_tables,
    const int*   __restrict__ context_lens,
    float*       __restrict__ ws)
{
    const int bid = blockIdx.x;
    const int p   = bid & (NPART - 1);
    const int kvh = (bid >> 4) & (KVH - 1);
    const int s   = bid >> 7;

    const int ctx = context_lens[s];
    const int t0  = p * PART;
    if (t0 >= ctx) return;

    __shared__ float p_lds[4][NG][WPT];   // per-wave probabilities (4 KB)
    __shared__ float o_lds[4][NG * HD];   // per-wave partial outputs (8 KB)
    __shared__ float ml_lds[4][8];        // per-wave m, l[4]

    const int tid  = threadIdx.x;
    const int wv   = tid >> 6;
    const int lane = tid & 63;
    const int tw0  = t0 + wv * WPT;
    const bool wact = (tw0 < ctx);

    const float* q = query + (size_t)s * (KVH * NG * HD) + (size_t)kvh * (NG * HD);

    float m_w = -1e30f;
    float l_w[NG] = {0.f, 0.f, 0.f, 0.f};

    if (wact) {
        // ---- QK: one token per lane ----
        const int t  = tw0 + lane;                     // < 4096 always: in-bounds
        const int bt = block_tables[s * MAXB + (t >> 4)];
        const float* kb = key_cache + (size_t)bt * (KVH * HD * BS)
                                    + (size_t)kvh * (HD * BS) + (t & 15) * 8;

        float sc[NG] = {0.f, 0.f, 0.f, 0.f};
        #pragma unroll
        for (int j = 0; j < 16; ++j) {
            const float4 ka = *(const float4*)(kb + j * 128);
            const float4 kc = *(const float4*)(kb + j * 128 + 4);
            #pragma unroll
            for (int g = 0; g < NG; ++g) {
                sc[g] += q[g * HD + j * 8 + 0] * ka.x + q[g * HD + j * 8 + 1] * ka.y
                       + q[g * HD + j * 8 + 2] * ka.z + q[g * HD + j * 8 + 3] * ka.w
                       + q[g * HD + j * 8 + 4] * kc.x + q[g * HD + j * 8 + 5] * kc.y
                       + q[g * HD + j * 8 + 6] * kc.z + q[g * HD + j * 8 + 7] * kc.w;
            }
        }

        // new-token K correction: token ctx-1's key comes from the `key` input
        if (t == ctx - 1) {
            const float4* kn4 = (const float4*)(key + ((size_t)s * KVH + kvh) * HD);
            float ns[NG] = {0.f, 0.f, 0.f, 0.f};
            #pragma unroll
            for (int c = 0; c < 32; ++c) {
                const float4 k4 = kn4[c];
                #pragma unroll
                for (int g = 0; g < NG; ++g) {
                    ns[g] += q[g * HD + c * 4 + 0] * k4.x + q[g * HD + c * 4 + 1] * k4.y
                           + q[g * HD + c * 4 + 2] * k4.z + q[g * HD + c * 4 + 3] * k4.w;
                }
            }
            #pragma unroll
            for (int g = 0; g < NG; ++g) sc[g] = ns[g];
        }

        float mv;
        if (t < ctx) {
            #pragma unroll
            for (int g = 0; g < NG; ++g) sc[g] *= SCALE_F;
            mv = fmaxf(fmaxf(sc[0], sc[1]), fmaxf(sc[2], sc[3]));
        } else {
            #pragma unroll
            for (int g = 0; g < NG; ++g) sc[g] = -1e30f;
            mv = -1e30f;
        }

        // wave max (shared across the 4 heads: any m >= true max is valid)
        #pragma unroll
        for (int o = 32; o; o >>= 1) mv = fmaxf(mv, __shfl_xor(mv, o));
        m_w = mv;

        float pr[NG];
        #pragma unroll
        for (int g = 0; g < NG; ++g) {
            pr[g] = __expf(sc[g] - m_w);
            p_lds[wv][g][lane] = pr[g];
            l_w[g] = pr[g];
        }
        #pragma unroll
        for (int o = 32; o; o >>= 1) {
            l_w[0] += __shfl_xor(l_w[0], o);
            l_w[1] += __shfl_xor(l_w[1], o);
            l_w[2] += __shfl_xor(l_w[2], o);
            l_w[3] += __shfl_xor(l_w[3], o);
        }
    }

    if (lane == 0) {
        ml_lds[wv][0] = m_w;
        #pragma unroll
        for (int g = 0; g < NG; ++g) ml_lds[wv][1 + g] = l_w[g];
    }

    // ---- PV: wave-local, lane = d (two halves) ----
    if (wact) {
        const int nbv = min(4, (ctx - tw0 + 15) >> 4);  // valid 16-tok blocks in slice
        int btv[4];
        #pragma unroll
        for (int b = 0; b < 4; ++b)
            btv[b] = block_tables[s * MAXB + (tw0 >> 4) + b];  // wave-uniform, in-bounds

        const int tl = ctx - 1 - tw0;                   // new-token slot within slice
        const float4* pl4 = (const float4*)&p_lds[wv][0][0];

        #pragma unroll 2
        for (int half = 0; half < 2; ++half) {
            const int d = lane + half * 64;
            float a[NG] = {0.f, 0.f, 0.f, 0.f};
            for (int b = 0; b < nbv; ++b) {
                const float* vb = value_cache + (size_t)btv[b] * (KVH * HD * BS)
                                              + (size_t)kvh * (HD * BS) + d * BS;
                #pragma unroll
                for (int c = 0; c < 4; ++c) {
                    const float4 v4 = *(const float4*)(vb + c * 4);
                    #pragma unroll
                    for (int g = 0; g < NG; ++g) {
                        const float4 pg = pl4[g * 16 + b * 4 + c];
                        a[g] += pg.x * v4.x + pg.y * v4.y + pg.z * v4.z + pg.w * v4.w;
                    }
                }
            }
            if (tl >= 0 && tl < WPT) {
                // replace stale cache V at token ctx-1 with the `value` input
                const int btn = block_tables[s * MAXB + ((ctx - 1) >> 4)];
                const float vold = value_cache[(size_t)btn * (KVH * HD * BS)
                                               + (size_t)kvh * (HD * BS) + d * BS + ((ctx - 1) & 15)];
                const float vnew = value[((size_t)s * KVH + kvh) * HD + d];
                const float dv = vnew - vold;
                #pragma unroll
                for (int g = 0; g < NG; ++g) a[g] += p_lds[wv][g][tl] * dv;
            }
            #pragma unroll
            for (int g = 0; g < NG; ++g) o_lds[wv][g * HD + d] = a[g];
        }
    } else {
        #pragma unroll
        for (int i = 0; i < 8; ++i) o_lds[wv][i * 64 + lane] = 0.f;
    }

    __syncthreads();   // the ONLY barrier: merge the 4 wave records

    const float m0 = ml_lds[0][0], m1 = ml_lds[1][0], m2 = ml_lds[2][0], m3 = ml_lds[3][0];
    const float M  = fmaxf(fmaxf(m0, m1), fmaxf(m2, m3));
    const float w0 = __expf(m0 - M), w1 = __expf(m1 - M);
    const float w2 = __expf(m2 - M), w3 = __expf(m3 - M);

    float* rec = ws + (size_t)bid * PSTRIDE;
    #pragma unroll
    for (int r = 0; r < 2; ++r) {
        const int idx = tid + r * 256;
        rec[idx] = w0 * o_lds[0][idx] + w1 * o_lds[1][idx]
                 + w2 * o_lds[2][idx] + w3 * o_lds[3][idx];
    }
    if (tid < NG) {
        rec[512 + tid] = w0 * ml_lds[0][1 + tid] + w1 * ml_lds[1][1 + tid]
                       + w2 * ml_lds[2][1 + tid] + w3 * ml_lds[3][1 + tid];
    }
    if (tid == 4) rec[516] = M;
}

// Kernel 2: LSE-combine partitions -> output. One (seq, kvh, g) per block.
__global__ __launch_bounds__(128) void pa_reduce_kernel(
    const float* __restrict__ ws,
    const int*   __restrict__ context_lens,
    float*       __restrict__ out)
{
    const int b    = blockIdx.x;        // ((s*KVH)+kvh)*NG + g
    const int g    = b & 3;
    const int pair = b >> 2;            // s*KVH + kvh
    const int s    = pair >> 3;
    const int kvh  = pair & 7;
    const int ctx  = context_lens[s];
    const int np   = (ctx + PART - 1) / PART;

    const int d = threadIdx.x;
    const float* base = ws + (size_t)pair * NPART * PSTRIDE;

    float M = -1e30f;
    for (int p2 = 0; p2 < np; ++p2) M = fmaxf(M, base[p2 * PSTRIDE + 516]);

    float L = 0.f, acc = 0.f;
    for (int p2 = 0; p2 < np; ++p2) {
        const float* rec = base + p2 * PSTRIDE;
        const float w = __expf(rec[516] - M);
        L   += w * rec[512 + g];
        acc += w * rec[g * HD + d];
    }

    out[(size_t)s * (KVH * NG * HD) + (size_t)(kvh * NG + g) * HD + d] = acc / L;
}

extern "C" void kernel_launch(void* const* d_in, const int* in_sizes, int n_in,
                              void* d_out, int out_size, void* d_ws, size_t ws_size,
                              hipStream_t stream) {
    const float* query       = (const float*)d_in[0];
    const float* key         = (const float*)d_in[1];
    const float* value       = (const float*)d_in[2];
    const float* key_cache   = (const float*)d_in[3];
    const float* value_cache = (const float*)d_in[4];
    const int*   block_tables  = (const int*)d_in[5];
    const int*   context_lens  = (const int*)d_in[6];
    // d_in[7] slot_mapping unused: slot is derivable from context_lens + block_tables

    float* out = (float*)d_out;
    float* ws  = (float*)d_ws;   // needs 16*8*16*520*4 = 4.26 MB

    pa_partial_kernel<<<NSEQ * KVH * NPART, 256, 0, stream>>>(
        query, key, value, key_cache, value_cache, block_tables, context_lens, ws);
    pa_reduce_kernel<<<NSEQ * KVH * NG, 128, 0, stream>>>(ws, context_lens, out);
}